// Round 6
// baseline (220.981 us; speedup 1.0000x reference)
//
#include <hip/hip_runtime.h>

#define SCAN_THREADS 256
#define EPT 8
#define CHUNK (SCAN_THREADS * EPT)   // 2048 elements per scan block

typedef int   v4i __attribute__((ext_vector_type(4)));
typedef float v4f __attribute__((ext_vector_type(4)));

// ---------------------------------------------------------------------------
// K1: filtered = residues * sigmoid(attrs @ w + b); scatter +/- into delta.
// tpre u tpost is a permutation of [0,2N) -> every slot written exactly once.
// Exact round-0 form (plain cached loads — nt variants measured neutral/worse).
__global__ void k1_filter_scatter(const float* __restrict__ attrs,
                                  const float* __restrict__ weight,
                                  const float* __restrict__ bias,
                                  const float* __restrict__ residues,
                                  const int* __restrict__ tpre,
                                  const int* __restrict__ tpost,
                                  float* __restrict__ delta,
                                  int N) {
    int u0 = (blockIdx.x * blockDim.x + threadIdx.x) * 2;
    v4f w0 = *(const v4f*)weight;
    v4f w1 = *(const v4f*)(weight + 4);
    float b = bias[0];
    if (u0 + 2 <= N) {
        float r0 = residues[u0], r1 = residues[u0 + 1];
        int pre0 = tpre[u0],  pre1 = tpre[u0 + 1];
        int pos0 = tpost[u0], pos1 = tpost[u0 + 1];
        v4f a00 = *(const v4f*)(attrs + (size_t)u0 * 8);
        v4f a01 = *(const v4f*)(attrs + (size_t)u0 * 8 + 4);
        v4f a10 = *(const v4f*)(attrs + (size_t)u0 * 8 + 8);
        v4f a11 = *(const v4f*)(attrs + (size_t)u0 * 8 + 12);
        float l0 = a00.x*w0.x + a00.y*w0.y + a00.z*w0.z + a00.w*w0.w +
                   a01.x*w1.x + a01.y*w1.y + a01.z*w1.z + a01.w*w1.w + b;
        float l1 = a10.x*w0.x + a10.y*w0.y + a10.z*w0.z + a10.w*w0.w +
                   a11.x*w1.x + a11.y*w1.y + a11.z*w1.z + a11.w*w1.w + b;
        float f0 = r0 / (1.0f + __expf(-l0));
        float f1 = r1 / (1.0f + __expf(-l1));
        delta[pre0] =  f0; delta[pre1] =  f1;
        delta[pos0] = -f0; delta[pos1] = -f1;
    } else {
        for (int u = u0; u < N; ++u) {
            float logit = b;
            #pragma unroll
            for (int k = 0; k < 8; ++k) logit += attrs[(size_t)u * 8 + k] * weight[k];
            float f = residues[u] / (1.0f + __expf(-logit));
            delta[tpre[u]]  =  f;
            delta[tpost[u]] = -f;
        }
    }
}

// ---------------------------------------------------------------------------
// K2: per-chunk partial sums (round-0 exact; measured faster than both the
// LDS-histogram (r4) and decoupled-lookback (r5) replacements).
__global__ void k2_partials(const float* __restrict__ delta,
                            float* __restrict__ partials, int T) {
    __shared__ float sdata[SCAN_THREADS / 64];
    int base = blockIdx.x * CHUNK + threadIdx.x * EPT;
    float s = 0.0f;
    if (base + EPT <= T) {
        v4f v0 = *(const v4f*)(delta + base);
        v4f v1 = *(const v4f*)(delta + base + 4);
        s = v0.x + v0.y + v0.z + v0.w + v1.x + v1.y + v1.z + v1.w;
    } else {
        for (int i = 0; i < EPT; ++i)
            if (base + i < T) s += delta[base + i];
    }
    #pragma unroll
    for (int d = 32; d > 0; d >>= 1) s += __shfl_down(s, d, 64);
    int lane = threadIdx.x & 63, wid = threadIdx.x >> 6;
    if (lane == 0) sdata[wid] = s;
    __syncthreads();
    if (threadIdx.x == 0)
        partials[blockIdx.x] = sdata[0] + sdata[1] + sdata[2] + sdata[3];
}

// ---------------------------------------------------------------------------
// K4: in-place inclusive scan of each chunk; each block derives its own
// offset by reducing partials[0..blockIdx.x) (L2-hot floats).
__global__ void k4_scan_chunks(float* __restrict__ data,
                               const float* __restrict__ partials, int T) {
    __shared__ float wavesums[SCAN_THREADS / 64];
    __shared__ float redsum[SCAN_THREADS / 64];
    int lane = threadIdx.x & 63, wid = threadIdx.x >> 6;

    float c = 0.0f;
    for (int i = threadIdx.x; i < blockIdx.x; i += SCAN_THREADS)
        c += partials[i];
    #pragma unroll
    for (int d = 32; d > 0; d >>= 1) c += __shfl_down(c, d, 64);
    if (lane == 0) redsum[wid] = c;

    int base = blockIdx.x * CHUNK + threadIdx.x * EPT;
    float v[EPT];
    bool full = (base + EPT <= T);
    if (full) {
        v4f v0 = *(const v4f*)(data + base);
        v4f v1 = *(const v4f*)(data + base + 4);
        v[0]=v0.x; v[1]=v0.y; v[2]=v0.z; v[3]=v0.w;
        v[4]=v1.x; v[5]=v1.y; v[6]=v1.z; v[7]=v1.w;
    } else {
        for (int i = 0; i < EPT; ++i)
            v[i] = (base + i < T) ? data[base + i] : 0.0f;
    }
    float run = 0.0f;
    #pragma unroll
    for (int i = 0; i < EPT; ++i) { run += v[i]; v[i] = run; }
    float tot = run;
    float x = tot;
    #pragma unroll
    for (int d = 1; d < 64; d <<= 1) {
        float y = __shfl_up(x, d, 64);
        if (lane >= d) x += y;
    }
    if (lane == 63) wavesums[wid] = x;
    __syncthreads();
    float woff = 0.0f, offset = redsum[0] + redsum[1] + redsum[2] + redsum[3];
    #pragma unroll
    for (int i = 0; i < SCAN_THREADS / 64; ++i)
        if (i < wid) woff += wavesums[i];
    float add = (x - tot) + woff + offset;
    if (full) {
        v4f o0 = { v[0]+add, v[1]+add, v[2]+add, v[3]+add };
        v4f o1 = { v[4]+add, v[5]+add, v[6]+add, v[7]+add };
        *(v4f*)(data + base)     = o0;
        *(v4f*)(data + base + 4) = o1;
    } else {
        for (int i = 0; i < EPT; ++i)
            if (base + i < T) data[base + i] = v[i] + add;
    }
}

// ---------------------------------------------------------------------------
// K6_DIRECT: out[i] = ycum[tpre[nop[i]]] — k5 folded into the gather.
// Removes k5's dispatch + its 500K gathers / 2MB stores / 2MB re-read; adds
// one tpre-gather layer (tpre = 2MB, L2-resident per XCD). 4 px/thread for
// deep TLP on the 3-level dependent chain (nop -> tpre -> ycum).
__global__ void k6_direct(const float* __restrict__ ycum,
                          const int* __restrict__ tpre,
                          const int* __restrict__ nop,
                          float* __restrict__ out, int P) {
    int i = (blockIdx.x * blockDim.x + threadIdx.x) * 4;
    if (i + 4 <= P) {
        v4i n = *(const v4i*)(nop + i);
        int t0 = tpre[n.x], t1 = tpre[n.y], t2 = tpre[n.z], t3 = tpre[n.w];
        v4f o = { ycum[t0], ycum[t1], ycum[t2], ycum[t3] };
        *(v4f*)(out + i) = o;
    } else {
        for (; i < P; ++i) out[i] = ycum[tpre[nop[i]]];
    }
}

extern "C" void kernel_launch(void* const* d_in, const int* in_sizes, int n_in,
                              void* d_out, int out_size, void* d_ws, size_t ws_size,
                              hipStream_t stream) {
    const float* weight   = (const float*)d_in[0];
    const float* bias     = (const float*)d_in[1];
    const float* residues = (const float*)d_in[2];
    const float* attrs    = (const float*)d_in[3];
    const int*   tpre     = (const int*)d_in[4];
    const int*   tpost    = (const int*)d_in[5];
    const int*   nop      = (const int*)d_in[6];
    float* out = (float*)d_out;

    const int N = in_sizes[2];        // 500,000
    const int T = 2 * N;              // 1,000,000
    const int P = out_size;           // 8,388,608
    const int numChunks = (T + CHUNK - 1) / CHUNK;   // 489

    // Only delta (T floats) + partials (numChunks floats) needed now (~4 MB).
    size_t need = (size_t)(T + 1024) * sizeof(float);

    float* delta;
    float* partials;
    if (ws_size >= need) {
        delta    = (float*)d_ws;
        partials = delta + T;
    } else {
        // Legacy last-resort tier (ws too small): delta aliases out.
        delta    = out;
        partials = (float*)d_ws;
    }

    k1_filter_scatter<<<(N / 2 + 255) / 256, 256, 0, stream>>>(
        attrs, weight, bias, residues, tpre, tpost, delta, N);
    k2_partials<<<numChunks, SCAN_THREADS, 0, stream>>>(delta, partials, T);
    k4_scan_chunks<<<numChunks, SCAN_THREADS, 0, stream>>>(delta, partials, T);

    int gatherBlocks = (P / 4 + 255) / 256;
    k6_direct<<<gatherBlocks, 256, 0, stream>>>(delta, tpre, nop, out, P);
}

// Round 7
// 163.472 us; speedup vs baseline: 1.3518x; 1.3518x over previous
//
#include <hip/hip_runtime.h>

#define SCAN_THREADS 256
#define EPT 8
#define CHUNK (SCAN_THREADS * EPT)   // 2048 elements per scan block

typedef int   v2i __attribute__((ext_vector_type(2)));
typedef int   v4i __attribute__((ext_vector_type(4)));
typedef float v2f __attribute__((ext_vector_type(2)));
typedef float v4f __attribute__((ext_vector_type(4)));

// ---------------------------------------------------------------------------
// K1a: fval[u] = residues[u] * sigmoid(attrs[u] @ w + b). Pure streaming
// (20MB in, 2MB linear out) — NO scatter, so L2 churn here is harmless.
__global__ void k1a_filter(const float* __restrict__ attrs,
                           const float* __restrict__ weight,
                           const float* __restrict__ bias,
                           const float* __restrict__ residues,
                           float* __restrict__ fval,
                           int N) {
    int u0 = (blockIdx.x * blockDim.x + threadIdx.x) * 2;
    v4f w0 = *(const v4f*)weight;
    v4f w1 = *(const v4f*)(weight + 4);
    float b = bias[0];
    if (u0 + 2 <= N) {
        v2f rr = *(const v2f*)(residues + u0);
        v4f a00 = *(const v4f*)(attrs + (size_t)u0 * 8);
        v4f a01 = *(const v4f*)(attrs + (size_t)u0 * 8 + 4);
        v4f a10 = *(const v4f*)(attrs + (size_t)u0 * 8 + 8);
        v4f a11 = *(const v4f*)(attrs + (size_t)u0 * 8 + 12);
        float l0 = a00.x*w0.x + a00.y*w0.y + a00.z*w0.z + a00.w*w0.w +
                   a01.x*w1.x + a01.y*w1.y + a01.z*w1.z + a01.w*w1.w + b;
        float l1 = a10.x*w0.x + a10.y*w0.y + a10.z*w0.z + a10.w*w0.w +
                   a11.x*w1.x + a11.y*w1.y + a11.z*w1.z + a11.w*w1.w + b;
        v2f f = { rr.x / (1.0f + __expf(-l0)), rr.y / (1.0f + __expf(-l1)) };
        *(v2f*)(fval + u0) = f;
    } else {
        for (int u = u0; u < N; ++u) {
            float logit = b;
            #pragma unroll
            for (int k = 0; k < 8; ++k) logit += attrs[(size_t)u * 8 + k] * weight[k];
            fval[u] = residues[u] / (1.0f + __expf(-logit));
        }
    }
}

// ---------------------------------------------------------------------------
// K1b: scatter only. delta[tpre[u]] = +fval[u]; delta[tpost[u]] = -fval[u].
// Streams (6MB) are nt-loaded so they don't evict the 4MB delta scatter
// target from per-XCD L2 — the round-6 decomposition showed the fused k1
// (20MB stream + scatter) was ~90-100us of L2 thrash; this isolates it.
__global__ void k1b_scatter(const float* __restrict__ fval,
                            const int* __restrict__ tpre,
                            const int* __restrict__ tpost,
                            float* __restrict__ delta,
                            int N) {
    int u0 = (blockIdx.x * blockDim.x + threadIdx.x) * 2;
    if (u0 + 2 <= N) {
        v2f f  = __builtin_nontemporal_load((const v2f*)(fval + u0));
        v2i pr = __builtin_nontemporal_load((const v2i*)(tpre + u0));
        v2i po = __builtin_nontemporal_load((const v2i*)(tpost + u0));
        delta[pr.x] =  f.x; delta[pr.y] =  f.y;
        delta[po.x] = -f.x; delta[po.y] = -f.y;
    } else {
        for (int u = u0; u < N; ++u) {
            float f = fval[u];
            delta[tpre[u]]  =  f;
            delta[tpost[u]] = -f;
        }
    }
}

// ---------------------------------------------------------------------------
// K1 fused (fallback tier only — round-0 exact form).
__global__ void k1_filter_scatter(const float* __restrict__ attrs,
                                  const float* __restrict__ weight,
                                  const float* __restrict__ bias,
                                  const float* __restrict__ residues,
                                  const int* __restrict__ tpre,
                                  const int* __restrict__ tpost,
                                  float* __restrict__ delta,
                                  int N) {
    int u0 = (blockIdx.x * blockDim.x + threadIdx.x) * 2;
    v4f w0 = *(const v4f*)weight;
    v4f w1 = *(const v4f*)(weight + 4);
    float b = bias[0];
    if (u0 + 2 <= N) {
        float r0 = residues[u0], r1 = residues[u0 + 1];
        int pre0 = tpre[u0],  pre1 = tpre[u0 + 1];
        int pos0 = tpost[u0], pos1 = tpost[u0 + 1];
        v4f a00 = *(const v4f*)(attrs + (size_t)u0 * 8);
        v4f a01 = *(const v4f*)(attrs + (size_t)u0 * 8 + 4);
        v4f a10 = *(const v4f*)(attrs + (size_t)u0 * 8 + 8);
        v4f a11 = *(const v4f*)(attrs + (size_t)u0 * 8 + 12);
        float l0 = a00.x*w0.x + a00.y*w0.y + a00.z*w0.z + a00.w*w0.w +
                   a01.x*w1.x + a01.y*w1.y + a01.z*w1.z + a01.w*w1.w + b;
        float l1 = a10.x*w0.x + a10.y*w0.y + a10.z*w0.z + a10.w*w0.w +
                   a11.x*w1.x + a11.y*w1.y + a11.z*w1.z + a11.w*w1.w + b;
        float f0 = r0 / (1.0f + __expf(-l0));
        float f1 = r1 / (1.0f + __expf(-l1));
        delta[pre0] =  f0; delta[pre1] =  f1;
        delta[pos0] = -f0; delta[pos1] = -f1;
    } else {
        for (int u = u0; u < N; ++u) {
            float logit = b;
            #pragma unroll
            for (int k = 0; k < 8; ++k) logit += attrs[(size_t)u * 8 + k] * weight[k];
            float f = residues[u] / (1.0f + __expf(-logit));
            delta[tpre[u]]  =  f;
            delta[tpost[u]] = -f;
        }
    }
}

// ---------------------------------------------------------------------------
// K2: per-chunk partial sums (round-0 exact).
__global__ void k2_partials(const float* __restrict__ delta,
                            float* __restrict__ partials, int T) {
    __shared__ float sdata[SCAN_THREADS / 64];
    int base = blockIdx.x * CHUNK + threadIdx.x * EPT;
    float s = 0.0f;
    if (base + EPT <= T) {
        v4f v0 = *(const v4f*)(delta + base);
        v4f v1 = *(const v4f*)(delta + base + 4);
        s = v0.x + v0.y + v0.z + v0.w + v1.x + v1.y + v1.z + v1.w;
    } else {
        for (int i = 0; i < EPT; ++i)
            if (base + i < T) s += delta[base + i];
    }
    #pragma unroll
    for (int d = 32; d > 0; d >>= 1) s += __shfl_down(s, d, 64);
    int lane = threadIdx.x & 63, wid = threadIdx.x >> 6;
    if (lane == 0) sdata[wid] = s;
    __syncthreads();
    if (threadIdx.x == 0)
        partials[blockIdx.x] = sdata[0] + sdata[1] + sdata[2] + sdata[3];
}

// ---------------------------------------------------------------------------
// K4: in-place inclusive scan of each chunk (round-0 exact).
__global__ void k4_scan_chunks(float* __restrict__ data,
                               const float* __restrict__ partials, int T) {
    __shared__ float wavesums[SCAN_THREADS / 64];
    __shared__ float redsum[SCAN_THREADS / 64];
    int lane = threadIdx.x & 63, wid = threadIdx.x >> 6;

    float c = 0.0f;
    for (int i = threadIdx.x; i < blockIdx.x; i += SCAN_THREADS)
        c += partials[i];
    #pragma unroll
    for (int d = 32; d > 0; d >>= 1) c += __shfl_down(c, d, 64);
    if (lane == 0) redsum[wid] = c;

    int base = blockIdx.x * CHUNK + threadIdx.x * EPT;
    float v[EPT];
    bool full = (base + EPT <= T);
    if (full) {
        v4f v0 = *(const v4f*)(data + base);
        v4f v1 = *(const v4f*)(data + base + 4);
        v[0]=v0.x; v[1]=v0.y; v[2]=v0.z; v[3]=v0.w;
        v[4]=v1.x; v[5]=v1.y; v[6]=v1.z; v[7]=v1.w;
    } else {
        for (int i = 0; i < EPT; ++i)
            v[i] = (base + i < T) ? data[base + i] : 0.0f;
    }
    float run = 0.0f;
    #pragma unroll
    for (int i = 0; i < EPT; ++i) { run += v[i]; v[i] = run; }
    float tot = run;
    float x = tot;
    #pragma unroll
    for (int d = 1; d < 64; d <<= 1) {
        float y = __shfl_up(x, d, 64);
        if (lane >= d) x += y;
    }
    if (lane == 63) wavesums[wid] = x;
    __syncthreads();
    float woff = 0.0f, offset = redsum[0] + redsum[1] + redsum[2] + redsum[3];
    #pragma unroll
    for (int i = 0; i < SCAN_THREADS / 64; ++i)
        if (i < wid) woff += wavesums[i];
    float add = (x - tot) + woff + offset;
    if (full) {
        v4f o0 = { v[0]+add, v[1]+add, v[2]+add, v[3]+add };
        v4f o1 = { v[4]+add, v[5]+add, v[6]+add, v[7]+add };
        *(v4f*)(data + base)     = o0;
        *(v4f*)(data + base + 4) = o1;
    } else {
        for (int i = 0; i < EPT; ++i)
            if (base + i < T) data[base + i] = v[i] + add;
    }
}

// ---------------------------------------------------------------------------
// K5: vnode[u] = ycum[tpre[u]] (round-0 exact; vnode intermediate is what
// keeps k6's gather table at 2MB — round 6 proved removing it explodes FETCH).
__global__ void k5_node_values(const float* __restrict__ ycum,
                               const int* __restrict__ tpre,
                               float* __restrict__ vnode, int N) {
    int u0 = (blockIdx.x * blockDim.x + threadIdx.x) * 2;
    if (u0 + 2 <= N) {
        int t0 = tpre[u0], t1 = tpre[u0 + 1];
        float y0 = ycum[t0], y1 = ycum[t1];
        vnode[u0] = y0; vnode[u0 + 1] = y1;
    } else {
        for (int u = u0; u < N; ++u) vnode[u] = ycum[tpre[u]];
    }
}

// ---------------------------------------------------------------------------
// K6: per-pixel gather, 8 px/thread (round-0 exact: plain cached loads/stores).
__global__ void k6_gather(const float* __restrict__ vnode,
                          const int* __restrict__ nop,
                          float* __restrict__ out, int P) {
    int i = (blockIdx.x * blockDim.x + threadIdx.x) * 8;
    if (i + 8 <= P) {
        v4i n0 = *(const v4i*)(nop + i);
        v4i n1 = *(const v4i*)(nop + i + 4);
        v4f o0 = { vnode[n0.x], vnode[n0.y], vnode[n0.z], vnode[n0.w] };
        v4f o1 = { vnode[n1.x], vnode[n1.y], vnode[n1.z], vnode[n1.w] };
        *(v4f*)(out + i)     = o0;
        *(v4f*)(out + i + 4) = o1;
    } else {
        for (; i < P; ++i) out[i] = vnode[nop[i]];
    }
}

// K6 fallback: direct double gather (tiny-ws tier only).
__global__ void k6_direct(const float* __restrict__ ycum,
                          const int* __restrict__ tpre,
                          const int* __restrict__ nop,
                          float* __restrict__ out, int P) {
    int i = (blockIdx.x * blockDim.x + threadIdx.x) * 4;
    if (i + 4 <= P) {
        v4i n = *(const v4i*)(nop + i);
        v4f o = { ycum[tpre[n.x]], ycum[tpre[n.y]], ycum[tpre[n.z]], ycum[tpre[n.w]] };
        *(v4f*)(out + i) = o;
    } else {
        for (; i < P; ++i) out[i] = ycum[tpre[nop[i]]];
    }
}

extern "C" void kernel_launch(void* const* d_in, const int* in_sizes, int n_in,
                              void* d_out, int out_size, void* d_ws, size_t ws_size,
                              hipStream_t stream) {
    const float* weight   = (const float*)d_in[0];
    const float* bias     = (const float*)d_in[1];
    const float* residues = (const float*)d_in[2];
    const float* attrs    = (const float*)d_in[3];
    const int*   tpre     = (const int*)d_in[4];
    const int*   tpost    = (const int*)d_in[5];
    const int*   nop      = (const int*)d_in[6];
    float* out = (float*)d_out;

    const int N = in_sizes[2];        // 500,000
    const int T = 2 * N;              // 1,000,000
    const int P = out_size;           // 8,388,608
    const int numChunks = (T + CHUNK - 1) / CHUNK;   // 489

    size_t needSplit = (size_t)(T + N + N + 1024) * sizeof(float);  // delta+vnode+fval+partials
    size_t needFull  = (size_t)(T + N + 1024) * sizeof(float);      // round-0 layout
    size_t needMid   = (size_t)(N + 1024) * sizeof(float);

    const int nodeBlocks = (N / 2 + 255) / 256;

    if (ws_size >= needSplit) {
        float* delta    = (float*)d_ws;
        float* vnode    = delta + T;
        float* fval     = vnode + N;
        float* partials = fval + N;
        k1a_filter<<<nodeBlocks, 256, 0, stream>>>(
            attrs, weight, bias, residues, fval, N);
        k1b_scatter<<<nodeBlocks, 256, 0, stream>>>(
            fval, tpre, tpost, delta, N);
        k2_partials<<<numChunks, SCAN_THREADS, 0, stream>>>(delta, partials, T);
        k4_scan_chunks<<<numChunks, SCAN_THREADS, 0, stream>>>(delta, partials, T);
        k5_node_values<<<nodeBlocks, 256, 0, stream>>>(delta, tpre, vnode, N);
        k6_gather<<<(P / 8 + 255) / 256, 256, 0, stream>>>(vnode, nop, out, P);
    } else if (ws_size >= needFull) {
        float* delta    = (float*)d_ws;
        float* vnode    = delta + T;
        float* partials = vnode + N;
        k1_filter_scatter<<<nodeBlocks, 256, 0, stream>>>(
            attrs, weight, bias, residues, tpre, tpost, delta, N);
        k2_partials<<<numChunks, SCAN_THREADS, 0, stream>>>(delta, partials, T);
        k4_scan_chunks<<<numChunks, SCAN_THREADS, 0, stream>>>(delta, partials, T);
        k5_node_values<<<nodeBlocks, 256, 0, stream>>>(delta, tpre, vnode, N);
        k6_gather<<<(P / 8 + 255) / 256, 256, 0, stream>>>(vnode, nop, out, P);
    } else if (ws_size >= needMid) {
        float* delta    = out;        // dead until k6 rewrites it fully
        float* vnode    = (float*)d_ws;
        float* partials = vnode + N;
        k1_filter_scatter<<<nodeBlocks, 256, 0, stream>>>(
            attrs, weight, bias, residues, tpre, tpost, delta, N);
        k2_partials<<<numChunks, SCAN_THREADS, 0, stream>>>(delta, partials, T);
        k4_scan_chunks<<<numChunks, SCAN_THREADS, 0, stream>>>(delta, partials, T);
        k5_node_values<<<nodeBlocks, 256, 0, stream>>>(delta, tpre, vnode, N);
        k6_gather<<<(P / 8 + 255) / 256, 256, 0, stream>>>(vnode, nop, out, P);
    } else {
        float* delta    = out;
        float* partials = (float*)d_ws;
        k1_filter_scatter<<<nodeBlocks, 256, 0, stream>>>(
            attrs, weight, bias, residues, tpre, tpost, delta, N);
        k2_partials<<<numChunks, SCAN_THREADS, 0, stream>>>(delta, partials, T);
        k4_scan_chunks<<<numChunks, SCAN_THREADS, 0, stream>>>(delta, partials, T);
        k6_direct<<<(P / 4 + 255) / 256, 256, 0, stream>>>(delta, tpre, nop, out, P);
    }
}